// Round 12
// baseline (1126.605 us; speedup 1.0000x reference)
//
#include <hip/hip_runtime.h>

#define B_ 128
#define T_ 1000
#define NI 64
#define NH 256
#define DT_ 0.05f
#define GAMMA_ 2.7f
#define EPS_ 4.7f
#define BTH (128u*1000u*256u)

typedef float f2 __attribute__((ext_vector_type(2)));

// DPP move: returns partner lane's value per CTRL (VALU pipe).
template <int CTRL>
__device__ __forceinline__ float dppMov(float v) {
    return __int_as_float(__builtin_amdgcn_update_dpp(
        __float_as_int(v), __float_as_int(v), CTRL, 0xF, 0xF, false));
}

// 8 FMAs as 4 packed v_pk_fma_f32: broadcast h-scalar into 4 column-pair accs.
#define FMA8(hv, w01, w23, w45, w67) {                     \
    const f2 hh = {(hv), (hv)};                            \
    ac01 = __builtin_elementwise_fma(hh, (w01), ac01);     \
    ac23 = __builtin_elementwise_fma(hh, (w23), ac23);     \
    ac45 = __builtin_elementwise_fma(hh, (w45), ac45);     \
    ac67 = __builtin_elementwise_fma(hh, (w67), ac67);     \
}

// One step of the scan. P = LDS buffer parity (compile-time).
// Reads hy from hyb[P], writes new hy to hyb[P^1].
#define STEP(P, tcur) {                                                        \
    const int tn = ((tcur) + 1 < T_) ? (tcur) + 1 : (tcur);                    \
    const float4 xn = *(const float4*)&x[((size_t)bT + tn) * NI + 4 * hex];    \
    const float* hs = (P) ? rs1 : rs0;                                         \
    const float4 h0v = *(const float4*)(hs + 0);                               \
    const float4 h1v = *(const float4*)(hs + 4);                               \
    const float4 h2v = *(const float4*)(hs + 8);                               \
    const float4 h3v = *(const float4*)(hs + 12);                              \
    f2 ac01 = {0.f, 0.f}, ac23 = {0.f, 0.f};                                   \
    f2 ac45 = {0.f, 0.f}, ac67 = {0.f, 0.f};                                   \
    FMA8(h0v.x, ha01[0],  ha23[0],  ha45[0],  ha67[0]);                        \
    FMA8(h0v.y, ha01[1],  ha23[1],  ha45[1],  ha67[1]);                        \
    FMA8(h0v.z, ha01[2],  ha23[2],  ha45[2],  ha67[2]);                        \
    FMA8(h0v.w, ha01[3],  ha23[3],  ha45[3],  ha67[3]);                        \
    FMA8(h1v.x, ha01[4],  ha23[4],  ha45[4],  ha67[4]);                        \
    FMA8(h1v.y, ha01[5],  ha23[5],  ha45[5],  ha67[5]);                        \
    FMA8(h1v.z, ha01[6],  ha23[6],  ha45[6],  ha67[6]);                        \
    FMA8(h1v.w, ha01[7],  ha23[7],  ha45[7],  ha67[7]);                        \
    FMA8(h2v.x, ha01[8],  ha23[8],  ha45[8],  ha67[8]);                        \
    FMA8(h2v.y, ha01[9],  ha23[9],  ha45[9],  ha67[9]);                        \
    FMA8(h2v.z, ha01[10], ha23[10], ha45[10], ha67[10]);                       \
    FMA8(h2v.w, ha01[11], ha23[11], ha45[11], ha67[11]);                       \
    FMA8(h3v.x, ha01[12], ha23[12], ha45[12], ha67[12]);                       \
    FMA8(h3v.y, ha01[13], ha23[13], ha45[13], ha67[13]);                       \
    FMA8(h3v.z, ha01[14], ha23[14], ha45[14], ha67[14]);                       \
    FMA8(h3v.w, ha01[15], ha23[15], ha45[15], ha67[15]);                       \
    FMA8(xcur.x, xa01[0], xa23[0], xa45[0], xa67[0]);                          \
    FMA8(xcur.y, xa01[1], xa23[1], xa45[1], xa67[1]);                          \
    FMA8(xcur.z, xa01[2], xa23[2], xa45[2], xa67[2]);                          \
    FMA8(xcur.w, xa01[3], xa23[3], xa45[3], xa67[3]);                          \
    float a0 = ac01.x, a1 = ac01.y, a2 = ac23.x, a3 = ac23.y;                  \
    float a4 = ac45.x, a5 = ac45.y, a6 = ac67.x, a7 = ac67.y;                  \
    /* L1: xor7 mirror, full butterfly (any cross partner valid pre-select) */ \
    a0 += dppMov<0x141>(a0); a1 += dppMov<0x141>(a1);                          \
    a2 += dppMov<0x141>(a2); a3 += dppMov<0x141>(a3);                          \
    a4 += dppMov<0x141>(a4); a5 += dppMov<0x141>(a5);                          \
    a6 += dppMov<0x141>(a6); a7 += dppMov<0x141>(a7);                          \
    /* L2: xor1 recursive halving (keep col-bit0 == hex-bit0, export other) */ \
    float s0 = (b0 ? a1 : a0) + dppMov<0xB1>(b0 ? a0 : a1);                    \
    float s1 = (b0 ? a3 : a2) + dppMov<0xB1>(b0 ? a2 : a3);                    \
    float s2 = (b0 ? a5 : a4) + dppMov<0xB1>(b0 ? a4 : a5);                    \
    float s3 = (b0 ? a7 : a6) + dppMov<0xB1>(b0 ? a6 : a7);                    \
    /* L3: xor2 halving */                                                     \
    float t0 = (b1 ? s1 : s0) + dppMov<0x4E>(b1 ? s0 : s1);                    \
    float t1 = (b1 ? s3 : s2) + dppMov<0x4E>(b1 ? s2 : s3);                    \
    /* L4: pick col-bit2 slot; xor8 (row_ror:8) full butterfly (dup partner */ \
    /* hex+8 holds the SAME column, other k-half) */                           \
    float drv = b2 ? t1 : t0;                                                  \
    drv += dppMov<0x128>(drv);                                                 \
    /* spiking + oscillator update (spike from PRE-update u) */                \
    const float spk = (u > 1.0f) ? 1.0f : 0.0f;                                \
    const float ur  = (u > 1.0f) ? 0.0f : u;                                   \
    u  = fmaf(drv - ur, DT_, ur);            /* BIAS=0, RC=1 */                \
    hz = fmaf(DT_, fmaf(-EPS_, hz, fmaf(-GAMMA_, hy, u)), hz);                 \
    hy = fmaf(DT_, hz, hy);                                                    \
    if (hex < 8) {                                                             \
        *((P) ? wB : wA) = hy;               /* hy -> buffer P^1 */            \
        const size_t ob = (size_t)(bT + (tcur)) * NH + col;                    \
        out[ob]                    = hy;                                       \
        out[(size_t)BTH + ob]      = hz;                                       \
        out[(size_t)2 * BTH + ob]  = u;                                        \
        out[(size_t)3 * BTH + ob]  = spk;                                      \
    }                                                                          \
    asm volatile("s_waitcnt lgkmcnt(0)\n\ts_barrier" ::: "memory");            \
    xcur = xn;                                                                 \
}

// One block per batch element; persistent scan over all T steps.
// 512 threads: hex = tid&15 owns k-rows 16*hex..16*hex+15 (and x 4*hex..+3);
// cg = tid>>4 owns columns 8cg..8cg+7 (weights in registers as column-pair
// f2 vectors -> v_pk_fma_f32). hy broadcast via 2.5 KB double-buffered LDS;
// x loaded per-thread from global (L1-hot); outputs stored directly to
// global (coalesced 128B per wave per array).
//
// __launch_bounds__(512) with NO min-waves arg: 8-wave block residency caps
// regs at 256/wave structurally; total live ~220 should fit in ARCH VGPRs.
// R4/R10 both showed VGPR_Count=104 + ~160 phantom VALU instrs/step ==
// weights parked in AGPRs with accvgpr_read copies; this is the one-variable
// test of that hypothesis.
__global__ __launch_bounds__(512) void ron_scan(
    const float* __restrict__ x, const float* __restrict__ h2h,
    const float* __restrict__ x2h, float* __restrict__ out)
{
    // 16 sections of 16 floats, stride 20: section starts at banks
    // {0,20,8,28,16,4,24,12} x2 -> worst 2-way aliasing (free, m136).
    __shared__ __align__(16) float hyb[2][320];

    const int tid = threadIdx.x;
    const int hex = tid & 15;
    const int cg  = tid >> 4;              // 0..31
    const int b   = blockIdx.x;
    const int bT  = b * T_;
    const int col = 8 * cg + (hex & 7);    // column this lane's sums land on
    const bool b0 = hex & 1, b1 = hex & 2, b2 = hex & 4;

    // ---- stage weights into registers as column-pair f2 vectors ----
    f2 ha01[16], ha23[16], ha45[16], ha67[16];
    f2 xa01[4], xa23[4], xa45[4], xa67[4];
#pragma unroll
    for (int i = 0; i < 16; ++i) {
        float4 vA = *(const float4*)&h2h[(16 * hex + i) * NH + 8 * cg];
        float4 vB = *(const float4*)&h2h[(16 * hex + i) * NH + 8 * cg + 4];
        ha01[i] = (f2){vA.x, vA.y}; ha23[i] = (f2){vA.z, vA.w};
        ha45[i] = (f2){vB.x, vB.y}; ha67[i] = (f2){vB.z, vB.w};
    }
#pragma unroll
    for (int i = 0; i < 4; ++i) {
        float4 vA = *(const float4*)&x2h[(4 * hex + i) * NH + 8 * cg];
        float4 vB = *(const float4*)&x2h[(4 * hex + i) * NH + 8 * cg + 4];
        xa01[i] = (f2){vA.x, vA.y}; xa23[i] = (f2){vA.z, vA.w};
        xa45[i] = (f2){vB.x, vB.y}; xa67[i] = (f2){vB.z, vB.w};
    }

    if (tid < 320) ((float*)hyb)[tid] = 0.0f;   // hyb[0] = 0 (t=0 state)
    __syncthreads();

    // LDS pointers: reads at section hex; writes at owned col's slot.
    const float* const rs0 = &hyb[0][20 * hex];
    const float* const rs1 = &hyb[1][20 * hex];
    float* const wA = &hyb[1][20 * (col >> 4) + (col & 15)];  // used when P=0
    float* const wB = &hyb[0][20 * (col >> 4) + (col & 15)];  // used when P=1

    float u = 0.f, hz = 0.f, hy = 0.f;
    float4 xcur = *(const float4*)&x[(size_t)bT * NI + 4 * hex];

    for (int t = 0; t < T_; t += 2) {
        STEP(0, t)
        STEP(1, t + 1)
    }
}

extern "C" void kernel_launch(void* const* d_in, const int* in_sizes, int n_in,
                              void* d_out, int out_size, void* d_ws, size_t ws_size,
                              hipStream_t stream) {
    const float* x   = (const float*)d_in[0];
    const float* h2h = (const float*)d_in[1];
    const float* x2h = (const float*)d_in[2];
    float* out = (float*)d_out;
    ron_scan<<<B_, 512, 0, stream>>>(x, h2h, x2h, out);
}